// Round 7
// baseline (323.311 us; speedup 1.0000x reference)
//
#include <hip/hip_runtime.h>
#include <stdint.h>
#include <math.h>

// cdist-attention, bf16 MFMA pipeline. R7: back to m97-class 128x128/BK=32/
// 4-wave blocks (16 KiB LDS, ~150 regs) so THREE independent blocks co-reside
// per CU (m114 overlap mechanism: 912 TF @3blk/CU vs 320 @1blk/CU for the
// same m97 kernel). R4-R6's 256x256/8-wave/228-reg design capped at 1 block/CU
// (Occupancy 21%) and every schedule refinement stalled at ~435 TF.
// Kept from prior rounds (all verified): R1 numerics, R5 swizzle math
// (SQ_LDS_BANK_CONFLICT=0, refcheck'd), R6 XCD pinning (FETCH 111->37MB).
// Grid modes: 0:(x=col,y=row,z=batch) 1:(x=batch,y=col,z=row) 2:(x=row,y=col,z=batch).

typedef __attribute__((ext_vector_type(8))) __bf16 bf16x8;
typedef __attribute__((ext_vector_type(4))) float f32x4;

__device__ __forceinline__ unsigned short f2b(float f) {
    unsigned u = __float_as_uint(f);
    unsigned r = 0x7fffu + ((u >> 16) & 1u);
    return (unsigned short)((u + r) >> 16);
}
__device__ __forceinline__ float b2f(unsigned short h) {
    return __uint_as_float(((unsigned)h) << 16);
}

__device__ __forceinline__ void glds16(const unsigned short* src, unsigned short* dst) {
    __builtin_amdgcn_global_load_lds(
        (const __attribute__((address_space(1))) unsigned int*)src,
        (__attribute__((address_space(3))) unsigned int*)dst, 16, 0, 0);
}

__global__ __launch_bounds__(256) void castk(const float* __restrict__ src,
                                             unsigned short* __restrict__ dst, int n4) {
    int i = blockIdx.x * 256 + threadIdx.x;
    if (i >= n4) return;
    float4 v = ((const float4*)src)[i];
    ushort4 o;
    o.x = f2b(v.x); o.y = f2b(v.y); o.z = f2b(v.z); o.w = f2b(v.w);
    ((ushort4*)dst)[i] = o;
}

// MODE 0: row sum; MODE 1: row sum of squares. One wave per row.
template <int MODE>
__global__ __launch_bounds__(256) void rowreduce(const unsigned short* __restrict__ X,
                                                 int L, int rows, float* __restrict__ out) {
    int w = threadIdx.x >> 6, lane = threadIdx.x & 63;
    int row = blockIdx.x * 4 + w;
    if (row >= rows) return;
    const unsigned short* xr = X + (size_t)row * L;
    float s = 0.f;
    int passes = L >> 8;
    for (int p = 0; p < passes; ++p) {
        ushort4 u = *(const ushort4*)(xr + (p << 8) + lane * 4);
        float a = b2f(u.x), b = b2f(u.y), c = b2f(u.z), d = b2f(u.w);
        s += MODE ? (a * a + b * b + c * c + d * d) : (a + b + c + d);
    }
#pragma unroll
    for (int o = 32; o > 0; o >>= 1) s += __shfl_down(s, o);
    if (lane == 0) out[row] = s;
}

// C[m][n] = sum_k A[m][k]*B[n][k]. 128x128 tile, BK=32, 4 waves (2x2 of 64x64).
// EPI 0: store bf16.  EPI 1: scores epilogue.  EPI 2: store f32 = acc/aux1[row].
template <int EPI>
__global__ __launch_bounds__(256) void gemm128(
    const unsigned short* __restrict__ A, int lda, long long sA,
    const unsigned short* __restrict__ B, int ldb, long long sB,
    void* __restrict__ Cv, int ldc, long long sC,
    int Kd, int mode,
    const float* __restrict__ aux1, int sAux1,
    const float* __restrict__ aux2, int sAux2,
    float invs) {
    // [128 rows][32 k] per operand, chunk-swizzled, 8 KiB each -> 16 KiB total
    __shared__ __attribute__((aligned(128))) unsigned short As[128 * 32];
    __shared__ __attribute__((aligned(128))) unsigned short Bs[128 * 32];

    const int z = (mode == 1) ? blockIdx.x : blockIdx.z;
    const int jb = (mode == 0) ? blockIdx.x : blockIdx.y;
    const int ib = (mode == 1) ? blockIdx.z : ((mode == 2) ? blockIdx.x : blockIdx.y);
    const unsigned short* __restrict__ Ab = A + (size_t)z * sA;
    const unsigned short* __restrict__ Bb = B + (size_t)z * sB;
    const int i0 = ib * 128;
    const int j0 = jb * 128;
    const int tid = threadIdx.x;
    const int w = tid >> 6, lane = tid & 63;
    const int wr = w >> 1, wc = w & 1;          // 2 x 2 wave grid, 64x64 each
    const int c16 = lane & 15, kq = lane >> 4;  // frag col / k-octet

    // staging (R5-verified swizzle): LDS chunk f = tid (+256): row = f>>2,
    // stored chunk = f&3, logical chunk = (f&3) ^ ((row>>1)&3).
    // Rows 64..127 (f>=256) keep the same clog ((row+64)>>1 ≡ row>>1 mod 4).
    const int srow = tid >> 2;                         // 0..63
    const int clog = (tid & 3) ^ ((tid >> 3) & 3);
    const unsigned short* pA0 = Ab + (size_t)(i0 + srow) * lda + clog * 8;
    const unsigned short* pB0 = Bb + (size_t)(j0 + srow) * ldb + clog * 8;

    // frag reads (R5-verified): short-off = row*32 + ((kq ^ ((row>>1)&3))<<3),
    // row = {wr|wc}*64 + mi*16 + c16 -> (row>>1)&3 == (c16>>1)&3.
    const int sw8 = (kq ^ ((c16 >> 1) & 3)) << 3;      // shorts
    const int aoff = (wr * 64 + c16) * 32 + sw8;       // + mi*512
    const int boff = (wc * 64 + c16) * 32 + sw8;       // + ni*512

    f32x4 acc[4][4];
    const f32x4 zero = {0.f, 0.f, 0.f, 0.f};
#pragma unroll
    for (int a = 0; a < 4; ++a)
#pragma unroll
        for (int b = 0; b < 4; ++b) acc[a][b] = zero;

    const int nt = Kd >> 5;  // K-tiles of 32

    for (int t = 0; t < nt; ++t) {
        const int k0 = t << 5;
        // stage 128x32 A and B (2 glds16 per thread per operand)
        glds16(pA0 + k0, &As[tid * 8]);
        glds16(pA0 + (size_t)64 * lda + k0, &As[2048 + tid * 8]);
        glds16(pB0 + k0, &Bs[tid * 8]);
        glds16(pB0 + (size_t)64 * ldb + k0, &Bs[2048 + tid * 8]);
        asm volatile("s_waitcnt vmcnt(0)" ::: "memory");
        __syncthreads();

        bf16x8 af[4], bf[4];
#pragma unroll
        for (int mi = 0; mi < 4; ++mi)
            af[mi] = *(const bf16x8*)(&As[aoff + mi * 512]);
#pragma unroll
        for (int ni = 0; ni < 4; ++ni)
            bf[ni] = *(const bf16x8*)(&Bs[boff + ni * 512]);
#pragma unroll
        for (int mi = 0; mi < 4; ++mi)
#pragma unroll
            for (int ni = 0; ni < 4; ++ni)
                acc[mi][ni] = __builtin_amdgcn_mfma_f32_16x16x32_bf16(af[mi], bf[ni],
                                                                      acc[mi][ni], 0, 0, 0);
        __syncthreads();
    }

    // C/D layout: col = lane&15, row = (lane>>4)*4 + reg
    const int r4 = kq * 4;
    if constexpr (EPI == 0) {
        unsigned short* C = (unsigned short*)Cv + (size_t)z * sC;
#pragma unroll
        for (int mi = 0; mi < 4; ++mi)
#pragma unroll
            for (int ni = 0; ni < 4; ++ni) {
                const int row = i0 + wr * 64 + mi * 16 + r4;
                const int col = j0 + wc * 64 + ni * 16 + c16;
#pragma unroll
                for (int r = 0; r < 4; ++r)
                    C[(size_t)(row + r) * ldc + col] = f2b(acc[mi][ni][r]);
            }
    } else if constexpr (EPI == 1) {
        unsigned short* C = (unsigned short*)Cv + (size_t)z * sC;
        const float* q2b = aux1 + (size_t)z * sAux1;
        const float* k2b = aux2 + (size_t)z * sAux2;
#pragma unroll
        for (int mi = 0; mi < 4; ++mi)
#pragma unroll
            for (int ni = 0; ni < 4; ++ni) {
                const int row = i0 + wr * 64 + mi * 16 + r4;
                const int col = j0 + wc * 64 + ni * 16 + c16;
                const float k2v = k2b[col];
#pragma unroll
                for (int r = 0; r < 4; ++r) {
                    float d2 = q2b[row + r] + k2v - 2.0f * acc[mi][ni][r];
                    float e = __expf(sqrtf(fmaxf(d2, 0.f)) * invs);
                    C[(size_t)(row + r) * ldc + col] = f2b(e);
                }
            }
    } else {
        float* C = (float*)Cv + (size_t)z * sC;
        const float* lb = aux1 + (size_t)z * sAux1;
#pragma unroll
        for (int mi = 0; mi < 4; ++mi)
#pragma unroll
            for (int ni = 0; ni < 4; ++ni) {
                const int row = i0 + wr * 64 + mi * 16 + r4;
                const int col = j0 + wc * 64 + ni * 16 + c16;
#pragma unroll
                for (int r = 0; r < 4; ++r)
                    C[(size_t)(row + r) * ldc + col] = acc[mi][ni][r] / lb[row + r];
            }
    }
}

extern "C" void kernel_launch(void* const* d_in, const int* in_sizes, int n_in,
                              void* d_out, int out_size, void* d_ws, size_t ws_size,
                              hipStream_t stream) {
    const float* x = (const float*)d_in[0];
    const float* Wq = (const float*)d_in[1];
    const float* Wk = (const float*)d_in[2];
    const float* Wv = (const float*)d_in[3];
    const int Bz = 8, S = 2048, D = 768, F = 768;
    const int BS = Bz * S;  // 16384

    const size_t szX = (size_t)BS * D * 2;
    const size_t szW = (size_t)F * D * 2;
    const size_t szE = (size_t)Bz * S * S * 2;

    char* p = (char*)d_ws;
    unsigned short* xb = (unsigned short*)p;  p += szX;
    unsigned short* Wqb = (unsigned short*)p; p += szW;
    unsigned short* Wkb = (unsigned short*)p; p += szW;
    unsigned short* Wvb = (unsigned short*)p; p += szW;
    unsigned short* Qm = (unsigned short*)p;  p += szX;
    unsigned short* Km = (unsigned short*)p;  p += szX;
    unsigned short* VT = (unsigned short*)p;  p += szX;  // [F][BS]
    unsigned short* E = (unsigned short*)p;   p += szE;  // [Bz][S][S]
    float* q2 = (float*)p;   p += (size_t)BS * 4;
    float* k2 = (float*)p;   p += (size_t)BS * 4;
    float* lsum = (float*)p; p += (size_t)BS * 4;
    if ((size_t)(p - (char*)d_ws) > ws_size) return;  // ~164 MiB scratch required

    const float invs = 1.0f / sqrtf(768.0f);

    // 1) casts
    castk<<<(BS * D / 4 + 255) / 256, 256, 0, stream>>>(x, xb, BS * D / 4);
    castk<<<(F * D / 4 + 255) / 256, 256, 0, stream>>>(Wq, Wqb, F * D / 4);
    castk<<<(F * D / 4 + 255) / 256, 256, 0, stream>>>(Wk, Wkb, F * D / 4);
    castk<<<(F * D / 4 + 255) / 256, 256, 0, stream>>>(Wv, Wvb, F * D / 4);

    // 2) Q,K = x . W^T  (z=0 -> Wq, z=1 -> Wk)
    //    mode2 (x=rowTile): same row-panel across col-tiles lands on one XCD
    gemm128<0><<<dim3(BS / 128, F / 128, 2), 256, 0, stream>>>(
        xb, D, 0,
        Wqb, D, (long long)F * D,
        Qm, F, (long long)BS * F,
        D, 2, nullptr, 0, nullptr, 0, 0.f);

    //    V^T = Wv . x^T -> VT[f][s]; mode0: x=colTile -> B-panel XCD-local
    gemm128<0><<<dim3(BS / 128, F / 128, 1), 256, 0, stream>>>(
        Wvb, D, 0,
        xb, D, 0,
        VT, BS, 0,
        D, 0, nullptr, 0, nullptr, 0, 0.f);

    // 3) row norms of Q,K
    rowreduce<1><<<BS / 4, 256, 0, stream>>>(Qm, F, BS, q2);
    rowreduce<1><<<BS / 4, 256, 0, stream>>>(Km, F, BS, k2);

    // 4) E = exp(sqrt(max(q2+k2-2*Q.K^T,0))*invs); mode1: XCD i owns batch i
    gemm128<1><<<dim3(Bz, S / 128, S / 128), 256, 0, stream>>>(
        Qm, F, (long long)S * F,
        Km, F, (long long)S * F,
        E, S, (long long)S * S,
        F, 1, q2, S, k2, S, invs);

    // 5) l = rowsum(E)
    rowreduce<0><<<BS / 4, 256, 0, stream>>>(E, S, BS, lsum);

    // 6) out = (E . V) / l; mode1: XCD i reads the E_z it just wrote
    gemm128<2><<<dim3(Bz, F / 128, S / 128), 256, 0, stream>>>(
        E, S, (long long)S * S,
        VT, BS, (long long)S,
        d_out, F, (long long)S * F,
        S, 1, lsum, S, nullptr, 0, 0.f);
}